// Round 3
// baseline (623.142 us; speedup 1.0000x reference)
//
#include <hip/hip_runtime.h>
#include <hip/hip_bf16.h>

// Problem constants (fixed shapes from setup_inputs)
#define M_DIM 8192   // B*S = 4*2048
#define N_DIM 4096   // D_OUT
#define DK    4096   // D_IN
#define R_DIM 64
#define KX    4160   // DK + R_DIM (K-extended GEMM)
#define SPLITK 8
#define KCHUNK (DK / SPLITK)  // 512
// SCALE = ALPHA/K = 16/16 = 1.0

typedef __bf16 bf16x8 __attribute__((ext_vector_type(8)));
typedef float f32x4 __attribute__((ext_vector_type(4)));
typedef unsigned short ushort8 __attribute__((ext_vector_type(8)));

__device__ __forceinline__ unsigned short f2bf_rne(float f) {
  union { float f; unsigned int u; } v; v.f = f;
  unsigned int u = v.u;
  return (unsigned short)((u + 0x7fffu + ((u >> 16) & 1u)) >> 16);
}

__device__ __forceinline__ ushort8 cvt8(float4 f0, float4 f1) {
  ushort8 o;
  o[0] = f2bf_rne(f0.x); o[1] = f2bf_rne(f0.y);
  o[2] = f2bf_rne(f0.z); o[3] = f2bf_rne(f0.w);
  o[4] = f2bf_rne(f1.x); o[5] = f2bf_rne(f1.y);
  o[6] = f2bf_rne(f1.z); o[7] = f2bf_rne(f1.w);
  return o;
}

// async global->LDS, 16B per lane; lds dest is wave-uniform base + lane*16
__device__ __forceinline__ void load16_to_lds(const void* g, void* l) {
  __builtin_amdgcn_global_load_lds(
      (__attribute__((address_space(1))) void*)(unsigned long long)(const char*)g,
      (__attribute__((address_space(3))) void*)(unsigned int)(unsigned long long)(char*)l,
      16, 0, 0);
}

// ---------------- fused: x fp32 -> bf16 staging -> z split-K MFMA + xext write ----------------
// grid (M/128, SPLITK); block 256 (4 waves); per block: 128 rows x 512-K chunk.
// Register-prefetched global loads (stay in flight across barriers, unlike
// global_load_lds which forces vmcnt(0) drain at __syncthreads).
__global__ __launch_bounds__(256) void xz_kernel(
    const float* __restrict__ x, const float* __restrict__ A,
    unsigned short* __restrict__ xext, float* __restrict__ zpart) {
  __shared__ unsigned short As[128][32];  // 8 KB (x rows, bf16)
  __shared__ unsigned short Bs[64][32];   // 4 KB (A rows, bf16)

  const int tid = threadIdx.x;
  const int wave = tid >> 6;
  const int lane = tid & 63;
  const int rowBase = blockIdx.x * 128;
  const int kc = blockIdx.y;
  const int kBase = kc * KCHUNK;
  const int wm = wave * 32;

  // x staging: thread t -> row t>>1, col-half (t&1)*16 (16 floats/iter)
  const int xr = tid >> 1, xh = tid & 1;
  const float4* xsrc = (const float4*)(x + (size_t)(rowBase + xr) * DK + kBase + xh * 16);
  // A staging: thread t -> row t>>2, quarter (t&3)*8 (8 floats/iter)
  const int ar = tid >> 2, af = tid & 3;
  const float4* asrc = (const float4*)(A + (size_t)ar * DK + kBase + af * 8);

  unsigned short* xdst = xext + (size_t)(rowBase + xr) * KX + kBase + xh * 16;

  // preload iter 0
  float4 xv0 = xsrc[0], xv1 = xsrc[1], xv2 = xsrc[2], xv3 = xsrc[3];
  float4 av0 = asrc[0], av1 = asrc[1];

  f32x4 acc[2][4] = {};
  const int fr = lane & 15;
  const int fk = (lane >> 4) * 8;

  for (int k0 = 0; k0 < KCHUNK; k0 += 32) {
    ushort8 xb0 = cvt8(xv0, xv1);
    ushort8 xb1 = cvt8(xv2, xv3);
    ushort8 ab  = cvt8(av0, av1);
    __syncthreads();  // prior iter's ds_reads done before overwrite
    *(ushort8*)&As[xr][xh * 16]     = xb0;
    *(ushort8*)&As[xr][xh * 16 + 8] = xb1;
    *(ushort8*)&Bs[ar][af * 8]      = ab;
    // prefetch next iter (wave-uniform predicate)
    if (k0 + 32 < KCHUNK) {
      int f4 = (k0 + 32) >> 2;
      xv0 = xsrc[f4]; xv1 = xsrc[f4 + 1]; xv2 = xsrc[f4 + 2]; xv3 = xsrc[f4 + 3];
      av0 = asrc[f4]; av1 = asrc[f4 + 1];
    }
    __syncthreads();  // staging visible
    // persist bf16 x into xext (no ordering needed vs LDS)
    *(ushort8*)(xdst + k0)     = xb0;
    *(ushort8*)(xdst + k0 + 8) = xb1;

    bf16x8 afrag[2], bfrag[4];
#pragma unroll
    for (int i = 0; i < 2; ++i)
      afrag[i] = *(const bf16x8*)&As[wm + i * 16 + fr][fk];
#pragma unroll
    for (int j = 0; j < 4; ++j)
      bfrag[j] = *(const bf16x8*)&Bs[j * 16 + fr][fk];
#pragma unroll
    for (int i = 0; i < 2; ++i)
#pragma unroll
      for (int j = 0; j < 4; ++j)
        acc[i][j] = __builtin_amdgcn_mfma_f32_16x16x32_bf16(afrag[i], bfrag[j],
                                                            acc[i][j], 0, 0, 0);
  }

  const int quad = lane >> 4;
#pragma unroll
  for (int j = 0; j < 4; ++j) {
    int col = j * 16 + fr;
#pragma unroll
    for (int i = 0; i < 2; ++i) {
      int row0 = rowBase + wm + i * 16 + quad * 4;
#pragma unroll
      for (int r = 0; r < 4; ++r)
        zpart[((size_t)kc * M_DIM + row0 + r) * R_DIM + col] = acc[i][j][r];
    }
  }
}

// ---------------- W & B fp32 -> bf16 into wext [N][4160] ----------------
__global__ __launch_bounds__(256) void wcvt_kernel(
    const float* __restrict__ W, const float* __restrict__ Bm,
    unsigned short* __restrict__ wext) {
  int idx = blockIdx.x * 256 + threadIdx.x;  // 8-element chunk id; total 4096*520
  int row = idx / 520;
  int c8 = idx - row * 520;
  const float* src = (c8 < 512) ? (W + (size_t)row * DK + c8 * 8)
                                : (Bm + (size_t)row * R_DIM + (c8 - 512) * 8);
  float4 f0 = *(const float4*)src;
  float4 f1 = *(const float4*)(src + 4);
  *(ushort8*)(wext + (size_t)row * KX + c8 * 8) = cvt8(f0, f1);
}

// ---------------- reduce partials, soft top-k mask, write bf16 into x_ext tail ----------------
// one wave per row
__global__ __launch_bounds__(256) void mask_kernel(
    const float* __restrict__ zpart, unsigned short* __restrict__ xext) {
  const int wave = threadIdx.x >> 6;
  const int lane = threadIdx.x & 63;
  const int row = blockIdx.x * 4 + wave;

  float v = 0.f;
#pragma unroll
  for (int k = 0; k < SPLITK; ++k)
    v += zpart[((size_t)k * M_DIM + row) * R_DIM + lane];

  float a = fabsf(v);
  // rank-select the 16th-largest |z| (tie-safe): cnt_gt <= 15 < cnt_ge
  int cnt_gt = 0, cnt_ge = 0;
#pragma unroll
  for (int i = 0; i < 64; ++i) {
    float o = __shfl(a, i);
    cnt_gt += (o > a) ? 1 : 0;
    cnt_ge += (o >= a) ? 1 : 0;
  }
  float cand = (cnt_gt <= 15 && cnt_ge > 15) ? a : -1.f;
#pragma unroll
  for (int off = 32; off; off >>= 1) cand = fmaxf(cand, __shfl_xor(cand, off));
  float thr = cand;
  float mask = 1.f / (1.f + __expf(-(a - thr) * 10.0f));  // TEMP=0.1
  xext[(size_t)row * KX + DK + lane] = f2bf_rne(v * mask);  // SCALE == 1.0
}

// ---------------- main GEMM: out[m][n] = sum_k xext[m][k]*wext[n][k] + bias[n] ----------------
// 128x128 tile, BK=32, 4 waves in 2x2, 4x4 16x16x32 MFMA per wave (m97 structure)
__global__ __launch_bounds__(256) void gemm_kernel(
    const unsigned short* __restrict__ Ag,   // [M_DIM][KX] bf16
    const unsigned short* __restrict__ Bg,   // [N_DIM][KX] bf16
    const float* __restrict__ bias,
    float* __restrict__ out) {
  __shared__ unsigned short As[128][32];  // 8 KB
  __shared__ unsigned short Bs[128][32];  // 8 KB

  const int tid = threadIdx.x;
  const int wave = tid >> 6;
  const int lane = tid & 63;
  const int bn = blockIdx.x, bm = blockIdx.y;
  const int rowBase = bm * 128, colBase = bn * 128;
  const int wm = (wave & 1) * 64, wn = (wave >> 1) * 64;

  const int c0 = wave, c1 = wave + 4;
  const int srow = lane >> 2;
  const int sseg = (lane & 3) * 8;

  const unsigned short* aP0 = Ag + (size_t)(rowBase + c0 * 16 + srow) * KX + sseg;
  const unsigned short* aP1 = Ag + (size_t)(rowBase + c1 * 16 + srow) * KX + sseg;
  const unsigned short* bP0 = Bg + (size_t)(colBase + c0 * 16 + srow) * KX + sseg;
  const unsigned short* bP1 = Bg + (size_t)(colBase + c1 * 16 + srow) * KX + sseg;
  unsigned short* aL0 = &As[c0 * 16][0];
  unsigned short* aL1 = &As[c1 * 16][0];
  unsigned short* bL0 = &Bs[c0 * 16][0];
  unsigned short* bL1 = &Bs[c1 * 16][0];

  f32x4 acc[4][4] = {};
  const int fr = lane & 15;
  const int fk = (lane >> 4) * 8;

  for (int k0 = 0; k0 < KX; k0 += 32) {
    __syncthreads();
    load16_to_lds(aP0 + k0, aL0);
    load16_to_lds(aP1 + k0, aL1);
    load16_to_lds(bP0 + k0, bL0);
    load16_to_lds(bP1 + k0, bL1);
    __syncthreads();

    bf16x8 afrag[4], bfrag[4];
#pragma unroll
    for (int i = 0; i < 4; ++i)
      afrag[i] = *(const bf16x8*)&As[wm + i * 16 + fr][fk];
#pragma unroll
    for (int j = 0; j < 4; ++j)
      bfrag[j] = *(const bf16x8*)&Bs[wn + j * 16 + fr][fk];
#pragma unroll
    for (int i = 0; i < 4; ++i)
#pragma unroll
      for (int j = 0; j < 4; ++j)
        acc[i][j] = __builtin_amdgcn_mfma_f32_16x16x32_bf16(afrag[i], bfrag[j],
                                                            acc[i][j], 0, 0, 0);
  }

  // epilogue: C/D layout col=lane&15, row=(lane>>4)*4+reg
  const int quad = lane >> 4;
#pragma unroll
  for (int j = 0; j < 4; ++j) {
    int col = colBase + wn + j * 16 + fr;
    float bv = bias[col];
#pragma unroll
    for (int i = 0; i < 4; ++i) {
      int row0 = rowBase + wm + i * 16 + quad * 4;
#pragma unroll
      for (int r = 0; r < 4; ++r)
        out[(size_t)(row0 + r) * N_DIM + col] = acc[i][j][r] + bv;
    }
  }
}

extern "C" void kernel_launch(void* const* d_in, const int* in_sizes, int n_in,
                              void* d_out, int out_size, void* d_ws, size_t ws_size,
                              hipStream_t stream) {
  const float* x    = (const float*)d_in[0];  // (4,2048,4096)
  const float* A    = (const float*)d_in[1];  // (64,4096)
  const float* B    = (const float*)d_in[2];  // (4096,64)
  const float* W    = (const float*)d_in[3];  // (4096,4096)
  const float* bias = (const float*)d_in[4];  // (4096,)
  float* out = (float*)d_out;

  // workspace layout (all 16B-aligned):
  //   xext  [8192][4160] bf16  = 68.16 MB
  //   wext  [4096][4160] bf16  = 34.08 MB
  //   zpart [8][8192][64] fp32 = 16.78 MB   (total 119.0 MB)
  unsigned short* xext = (unsigned short*)d_ws;
  unsigned short* wext = xext + (size_t)M_DIM * KX;
  float*          zpart = (float*)(wext + (size_t)N_DIM * KX);

  // fused: x -> bf16 -> (xext write + z split-K partials)
  dim3 zgrid(M_DIM / 128, SPLITK);  // 64 x 8
  xz_kernel<<<zgrid, 256, 0, stream>>>(x, A, xext, zpart);
  // W,B -> wext
  wcvt_kernel<<<(N_DIM * (KX / 8) + 255) / 256, 256, 0, stream>>>(W, B, wext);
  // reduce + soft-topk mask -> x_ext[:, 4096:]
  mask_kernel<<<M_DIM / 4, 256, 0, stream>>>(zpart, xext);

  dim3 grid(N_DIM / 128, M_DIM / 128);  // 32 x 64
  gemm_kernel<<<grid, 256, 0, stream>>>(xext, wext, bias, out);
}